// Round 4
// baseline (334.569 us; speedup 1.0000x reference)
//
#include <hip/hip_runtime.h>

#define DIM 64
#define LN_EPS 1e-5f
#define XS_STRIDE 68

// ---------------- CSR build (once per call) ----------------

__global__ void k_zero(int* __restrict__ deg, int* __restrict__ counter, int n) {
    int i = blockIdx.x * blockDim.x + threadIdx.x;
    if (i < n) deg[i] = 0;
    if (i == 0) { counter[0] = 0; counter[1] = 0; }
}

__global__ void k_count(const int* __restrict__ dst, int* __restrict__ deg, int e_cnt) {
    int e = blockIdx.x * blockDim.x + threadIdx.x;
    if (e < e_cnt) atomicAdd(&deg[dst[e]], 1);
}

__global__ void k_reserve(const int* __restrict__ deg, int* __restrict__ rowstart,
                          int* __restrict__ cursor, float* __restrict__ dinv,
                          int* __restrict__ counter, int n) {
    int i = blockIdx.x * blockDim.x + threadIdx.x;
    if (i >= n) return;
    int d = deg[i];
    int s = atomicAdd(counter, d);
    rowstart[i] = s;
    cursor[i] = s;
    dinv[i] = rsqrtf((float)(d + 1));
}

// csr[pos] = src only (4 B/edge) — weights are folded into pre-scaled activations.
__global__ void k_fill(const int* __restrict__ src, const int* __restrict__ dst,
                       int* __restrict__ cursor, int* __restrict__ csr, int e_cnt) {
    int e = blockIdx.x * blockDim.x + threadIdx.x;
    if (e >= e_cnt) return;
    int s = src[e], d = dst[e];
    int pos = atomicAdd(&cursor[d], 1);
    csr[pos] = s;
}

// xs[i,:] = dinv[i] * x[i,:]   (float4 over n*16)
__global__ void k_prescale(const float* __restrict__ x, const float* __restrict__ dinv,
                           float* __restrict__ xs, int n16) {
    int i = blockIdx.x * blockDim.x + threadIdx.x;
    if (i >= n16) return;
    float di = dinv[i >> 4];
    float4 v = ((const float4*)x)[i];
    v.x *= di; v.y *= di; v.z *= di; v.w *= di;
    ((float4*)xs)[i] = v;
}

// ---------------- fused per-layer kernel ----------------
// Phase 1: each wave aggregates 16 rows (lane = feature) into the LDS x-tile:
//   agg[row] = dinv[row] * (xs_in[row] + sum_e xs_in[src_e])
// Phase 2: register-tile GEMM (4x4 per lane) + bias + LN + ReLU; output scaled
//   by dinv[row] for non-final layers (keeps the xs invariant).
__global__ __launch_bounds__(256) void k_layer(const int* __restrict__ rowstart,
                                               const int* __restrict__ deg,
                                               const float* __restrict__ dinv,
                                               const int* __restrict__ csr,
                                               const float* __restrict__ xs_in,
                                               const float* __restrict__ W,
                                               const float* __restrict__ b,
                                               const float* __restrict__ gamma,
                                               const float* __restrict__ beta,
                                               float* __restrict__ out, int n,
                                               int scale_out) {
    __shared__ float ws[DIM * DIM];
    __shared__ float xs[64 * XS_STRIDE];
    int t = threadIdx.x;
    int base = blockIdx.x * 64;

    {   // stage W: 4096 floats, float4-coalesced
        const float4* W4 = (const float4*)W;
        float4* ws4 = (float4*)ws;
#pragma unroll
        for (int i = 0; i < 4; i++) ws4[t + 256 * i] = W4[t + 256 * i];
    }

    int wave = __builtin_amdgcn_readfirstlane(t >> 6);  // force SGPR -> scalar loads
    int lane = t & 63;

    // ---- phase 1: aggregation into LDS tile ----
    for (int r = 0; r < 16; r++) {
        int lrow = wave * 16 + r;
        int row = base + lrow;
        float acc = 0.f;
        if (row < n) {
            acc = xs_in[(size_t)row * DIM + lane];  // self-loop (pre-scaled)
            int s0  = __builtin_amdgcn_readfirstlane(rowstart[row]);
            int cnt = __builtin_amdgcn_readfirstlane(deg[row]);
            float a1 = 0.f, a2 = 0.f, a3 = 0.f;
            int i = 0;
            for (; i + 4 <= cnt; i += 4) {
                int e0 = csr[s0 + i + 0];
                int e1 = csr[s0 + i + 1];
                int e2 = csr[s0 + i + 2];
                int e3 = csr[s0 + i + 3];
                acc += xs_in[(size_t)e0 * DIM + lane];
                a1  += xs_in[(size_t)e1 * DIM + lane];
                a2  += xs_in[(size_t)e2 * DIM + lane];
                a3  += xs_in[(size_t)e3 * DIM + lane];
            }
            for (; i < cnt; i++) acc += xs_in[(size_t)csr[s0 + i] * DIM + lane];
            acc = (acc + a1 + a2 + a3) * dinv[row];
        }
        xs[lrow * XS_STRIDE + lane] = acc;  // bank = (4*lrow+lane)%32 -> 2-way, free
    }
    __syncthreads();

    // ---- phase 2: register-tile GEMM + epilogue ----
    int l = t & 63;
    int rgrp = l >> 4;
    int c4 = l & 15;
    int row0 = wave * 16 + rgrp * 4;

    float4 acc[4];
#pragma unroll
    for (int j = 0; j < 4; j++) acc[j] = make_float4(0.f, 0.f, 0.f, 0.f);

    for (int kc = 0; kc < 16; kc++) {
        float4 w0 = *(const float4*)(ws + (4 * kc + 0) * DIM + c4 * 4);
        float4 w1 = *(const float4*)(ws + (4 * kc + 1) * DIM + c4 * 4);
        float4 w2 = *(const float4*)(ws + (4 * kc + 2) * DIM + c4 * 4);
        float4 w3 = *(const float4*)(ws + (4 * kc + 3) * DIM + c4 * 4);
#pragma unroll
        for (int j = 0; j < 4; j++) {
            float4 xv = *(const float4*)(xs + (row0 + j) * XS_STRIDE + kc * 4);
            acc[j].x = fmaf(xv.x, w0.x, acc[j].x);
            acc[j].y = fmaf(xv.x, w0.y, acc[j].y);
            acc[j].z = fmaf(xv.x, w0.z, acc[j].z);
            acc[j].w = fmaf(xv.x, w0.w, acc[j].w);
            acc[j].x = fmaf(xv.y, w1.x, acc[j].x);
            acc[j].y = fmaf(xv.y, w1.y, acc[j].y);
            acc[j].z = fmaf(xv.y, w1.z, acc[j].z);
            acc[j].w = fmaf(xv.y, w1.w, acc[j].w);
            acc[j].x = fmaf(xv.z, w2.x, acc[j].x);
            acc[j].y = fmaf(xv.z, w2.y, acc[j].y);
            acc[j].z = fmaf(xv.z, w2.z, acc[j].z);
            acc[j].w = fmaf(xv.z, w2.w, acc[j].w);
            acc[j].x = fmaf(xv.w, w3.x, acc[j].x);
            acc[j].y = fmaf(xv.w, w3.y, acc[j].y);
            acc[j].z = fmaf(xv.w, w3.z, acc[j].z);
            acc[j].w = fmaf(xv.w, w3.w, acc[j].w);
        }
    }

    float4 b4  = *(const float4*)(b + c4 * 4);
    float4 g4  = *(const float4*)(gamma + c4 * 4);
    float4 be4 = *(const float4*)(beta + c4 * 4);
#pragma unroll
    for (int j = 0; j < 4; j++) {
        int grow = base + row0 + j;
        if (grow >= n) continue;
        float4 v = make_float4(acc[j].x + b4.x, acc[j].y + b4.y,
                               acc[j].z + b4.z, acc[j].w + b4.w);
        float s = v.x + v.y + v.z + v.w;
        s += __shfl_xor(s, 1, 64);
        s += __shfl_xor(s, 2, 64);
        s += __shfl_xor(s, 4, 64);
        s += __shfl_xor(s, 8, 64);
        float mu = s * (1.0f / 64.0f);
        float4 d = make_float4(v.x - mu, v.y - mu, v.z - mu, v.w - mu);
        float q = d.x * d.x + d.y * d.y + d.z * d.z + d.w * d.w;
        q += __shfl_xor(q, 1, 64);
        q += __shfl_xor(q, 2, 64);
        q += __shfl_xor(q, 4, 64);
        q += __shfl_xor(q, 8, 64);
        float rstd = rsqrtf(q * (1.0f / 64.0f) + LN_EPS);
        float4 y = make_float4(fmaxf(fmaf(d.x * rstd, g4.x, be4.x), 0.f),
                               fmaxf(fmaf(d.y * rstd, g4.y, be4.y), 0.f),
                               fmaxf(fmaf(d.z * rstd, g4.z, be4.z), 0.f),
                               fmaxf(fmaf(d.w * rstd, g4.w, be4.w), 0.f));
        if (scale_out) {
            float dr = dinv[grow];
            y.x *= dr; y.y *= dr; y.z *= dr; y.w *= dr;
        }
        *(float4*)(out + (size_t)grow * DIM + c4 * 4) = y;
    }
}

// ---------------- launch ----------------

extern "C" void kernel_launch(void* const* d_in, const int* in_sizes, int n_in,
                              void* d_out, int out_size, void* d_ws, size_t ws_size,
                              hipStream_t stream) {
    const float* x      = (const float*)d_in[0];
    const int*   ei     = (const int*)  d_in[1];
    const float* Ws     = (const float*)d_in[2];
    const float* bs     = (const float*)d_in[3];
    const float* gammas = (const float*)d_in[4];
    const float* betas  = (const float*)d_in[5];
    float* out = (float*)d_out;

    int n = in_sizes[0] / DIM;
    int E = in_sizes[1] / 2;
    int n_layers = in_sizes[2] / (DIM * DIM);

    const int* srcp = ei;
    const int* dstp = ei + E;

    // ws: deg[n] | rowstart[n] | cursor[n] | dinv[n] | counter[2] | csr[E] int | xsA[n*64]
    int* deg      = (int*)d_ws;
    int* rowstart = deg + n;
    int* cursor   = rowstart + n;
    float* dinv   = (float*)(cursor + n);
    int* counter  = (int*)(dinv + n);
    int* csr      = counter + 2;
    float* xsA    = (float*)(csr + E);

    int nb_n = (n + 255) / 256;
    int nb_e = (E + 255) / 256;

    k_zero   <<<nb_n, 256, 0, stream>>>(deg, counter, n);
    k_count  <<<nb_e, 256, 0, stream>>>(dstp, deg, E);
    k_reserve<<<nb_n, 256, 0, stream>>>(deg, rowstart, cursor, dinv, counter, n);
    k_fill   <<<nb_e, 256, 0, stream>>>(srcp, dstp, cursor, csr, E);

    // Buffer chain: buf_i for layer-i input; buf_{n_layers} must be d_out.
    // Alternate xsA <-> d_out; buf_i = d_out when (n_layers - i) is even.
    float* buf0 = ((n_layers & 1) == 0) ? out : xsA;
    k_prescale<<<(n * 16 + 255) / 256, 256, 0, stream>>>(x, dinv, buf0, n * 16);

    int nb_tile = (n + 63) / 64;
    float* cur = buf0;
    for (int i = 0; i < n_layers; i++) {
        float* dst = (cur == xsA) ? out : xsA;
        if (i == n_layers - 1) dst = out;  // invariant: parity guarantees this
        int scale = (i == n_layers - 1) ? 0 : 1;
        k_layer<<<nb_tile, 256, 0, stream>>>(rowstart, deg, dinv, csr, cur,
                                             Ws + (size_t)i * DIM * DIM,
                                             bs + (size_t)i * DIM,
                                             gammas + (size_t)i * DIM,
                                             betas + (size_t)i * DIM,
                                             dst, n, scale);
        cur = dst;
    }
}

// Round 5
// 325.426 us; speedup vs baseline: 1.0281x; 1.0281x over previous
//
#include <hip/hip_runtime.h>

#define DIM 64
#define LN_EPS 1e-5f
#define XS_STRIDE 68
#define MAXNB 1024   // supports n <= 65536 (n = 50000 here)
#define EPB 4096     // edges per binA block

// ---------------- bucketed CSR build (once per call) ----------------
// bucket b = dst >> 6  (64 nodes per bucket, aligned with k_layer tiles)

__global__ void k_zero2(int* __restrict__ bcnt, int* __restrict__ bfill, int nb1) {
    int i = blockIdx.x * blockDim.x + threadIdx.x;
    if (i < nb1) { bcnt[i] = 0; bfill[i] = 0; }
}

// per-block LDS histogram of dst buckets -> atomic merge to global
__global__ __launch_bounds__(256) void k_countb(const int* __restrict__ dst,
                                                int* __restrict__ bcnt, int E, int nb) {
    __shared__ int h[MAXNB];
    int t = threadIdx.x;
    for (int i = t; i < nb; i += 256) h[i] = 0;
    __syncthreads();
    int e0 = blockIdx.x * EPB;
#pragma unroll 4
    for (int j = 0; j < EPB / 256; j++) {
        int e = e0 + j * 256 + t;
        if (e < E) atomicAdd(&h[dst[e] >> 6], 1);
    }
    __syncthreads();
    for (int i = t; i < nb; i += 256) if (h[i]) atomicAdd(&bcnt[i], h[i]);
}

// exclusive scan of bcnt[0..nb) -> bstart[0..nb]  (single block)
__global__ __launch_bounds__(256) void k_scanb(const int* __restrict__ bcnt,
                                               int* __restrict__ bstart, int nb) {
    __shared__ int wsum[4];
    int t = threadIdx.x;
    int c0 = t * 4;
    int x0 = (c0 + 0 < nb) ? bcnt[c0 + 0] : 0;
    int x1 = (c0 + 1 < nb) ? bcnt[c0 + 1] : 0;
    int x2 = (c0 + 2 < nb) ? bcnt[c0 + 2] : 0;
    int x3 = (c0 + 3 < nb) ? bcnt[c0 + 3] : 0;
    int s = x0 + x1 + x2 + x3;
    int lane = t & 63, wave = t >> 6;
    int incl = s;
#pragma unroll
    for (int d = 1; d < 64; d <<= 1) { int u = __shfl_up(incl, d, 64); if (lane >= d) incl += u; }
    if (lane == 63) wsum[wave] = incl;
    __syncthreads();
    int wo = 0;
    for (int w = 0; w < wave; w++) wo += wsum[w];
    int excl = wo + incl - s;
    if (c0 + 0 < nb) bstart[c0 + 0] = excl;
    if (c0 + 1 < nb) bstart[c0 + 1] = excl + x0;
    if (c0 + 2 < nb) bstart[c0 + 2] = excl + x0 + x1;
    if (c0 + 3 < nb) bstart[c0 + 3] = excl + x0 + x1 + x2;
    if (t == 255) bstart[nb] = wo + incl;   // total = E
}

// Pass A: LDS-sort a 4096-edge chunk by bucket, reserve global segments,
// write packed entries (src<<6 | dst&63) coalesced & time-local.
__global__ __launch_bounds__(256) void k_binA(const int* __restrict__ src,
                                              const int* __restrict__ dst,
                                              const int* __restrict__ bstart,
                                              int* __restrict__ bfill,
                                              int* __restrict__ ebuf, int E, int nb) {
    __shared__ int lhist[MAXNB];   // histogram, then reset to cursor
    __shared__ int lbase[MAXNB];
    __shared__ int gbase[MAXNB];
    __shared__ int staged[EPB];
    __shared__ int gpos[EPB];
    __shared__ int wsum[4];
    int t = threadIdx.x;
    for (int i = t; i < nb; i += 256) lhist[i] = 0;
    __syncthreads();

    int e0 = blockIdx.x * EPB;
    int ecnt = min(EPB, E - e0);
    int ss[EPB / 256], dd[EPB / 256];
    int ne = 0;
#pragma unroll
    for (int j = 0; j < EPB / 256; j++) {
        int e = e0 + j * 256 + t;
        if (e < E) { ss[ne] = src[e]; dd[ne] = dst[e]; ne++; }
    }
    for (int j = 0; j < ne; j++) atomicAdd(&lhist[dd[j] >> 6], 1);
    __syncthreads();

    {   // exclusive scan lhist -> lbase (lhist preserved)
        int c0 = t * 4;
        int x0 = (c0 + 0 < nb) ? lhist[c0 + 0] : 0;
        int x1 = (c0 + 1 < nb) ? lhist[c0 + 1] : 0;
        int x2 = (c0 + 2 < nb) ? lhist[c0 + 2] : 0;
        int x3 = (c0 + 3 < nb) ? lhist[c0 + 3] : 0;
        int s = x0 + x1 + x2 + x3;
        int lane = t & 63, wave = t >> 6;
        int incl = s;
#pragma unroll
        for (int d = 1; d < 64; d <<= 1) { int u = __shfl_up(incl, d, 64); if (lane >= d) incl += u; }
        if (lane == 63) wsum[wave] = incl;
        __syncthreads();
        int wo = 0;
        for (int w = 0; w < wave; w++) wo += wsum[w];
        int excl = wo + incl - s;
        if (c0 + 0 < nb) lbase[c0 + 0] = excl;
        if (c0 + 1 < nb) lbase[c0 + 1] = excl + x0;
        if (c0 + 2 < nb) lbase[c0 + 2] = excl + x0 + x1;
        if (c0 + 3 < nb) lbase[c0 + 3] = excl + x0 + x1 + x2;
    }
    __syncthreads();

    // reserve global segments, then reset lhist to serve as scatter cursor
    for (int i = t; i < nb; i += 256) {
        int c = lhist[i];
        gbase[i] = c ? (bstart[i] + atomicAdd(&bfill[i], c)) : 0;
        lhist[i] = 0;
    }
    __syncthreads();

    // scatter into staged (bucket-sorted order) + record final global position
    for (int j = 0; j < ne; j++) {
        int b = dd[j] >> 6;
        int ofs = atomicAdd(&lhist[b], 1);
        int p = lbase[b] + ofs;
        staged[p] = (ss[j] << 6) | (dd[j] & 63);
        gpos[p] = gbase[b] + ofs;
    }
    __syncthreads();

    // write out: consecutive i -> mostly-consecutive global addresses
    for (int i = t; i < ecnt; i += 256) ebuf[gpos[i]] = staged[i];
}

// Pass B: one block per bucket. Build deg/rowstart/dinv for its 64 nodes in
// LDS, scatter csr densely into the bucket's contiguous ~4 KB window.
__global__ __launch_bounds__(256) void k_binB(const int* __restrict__ bstart,
                                              const int* __restrict__ ebuf,
                                              int* __restrict__ deg,
                                              int* __restrict__ rowstart,
                                              float* __restrict__ dinv,
                                              int* __restrict__ csr, int n) {
    __shared__ int ldeg[64];
    __shared__ int lcur[64];
    int b = blockIdx.x;
    int t = threadIdx.x;
    int e0 = bstart[b], e1 = bstart[b + 1];
    if (t < 64) ldeg[t] = 0;
    __syncthreads();
    for (int i = e0 + t; i < e1; i += 256) atomicAdd(&ldeg[ebuf[i] & 63], 1);
    __syncthreads();
    if (t < 64) {   // wave 0: exclusive scan over 64 nodes
        int d = ldeg[t];
        int incl = d;
#pragma unroll
        for (int sh = 1; sh < 64; sh <<= 1) { int u = __shfl_up(incl, sh, 64); if (t >= sh) incl += u; }
        int excl = incl - d;
        lcur[t] = excl;
        int node = b * 64 + t;
        if (node < n) {
            deg[node] = d;
            rowstart[node] = e0 + excl;
            dinv[node] = rsqrtf((float)(d + 1));
        }
    }
    __syncthreads();
    for (int i = e0 + t; i < e1; i += 256) {
        int v = ebuf[i];
        int pos = atomicAdd(&lcur[v & 63], 1);
        csr[e0 + pos] = v >> 6;
    }
}

// xs[i,:] = dinv[i] * x[i,:]   (float4 over n*16)
__global__ void k_prescale(const float* __restrict__ x, const float* __restrict__ dinv,
                           float* __restrict__ xs, int n16) {
    int i = blockIdx.x * blockDim.x + threadIdx.x;
    if (i >= n16) return;
    float di = dinv[i >> 4];
    float4 v = ((const float4*)x)[i];
    v.x *= di; v.y *= di; v.z *= di; v.w *= di;
    ((float4*)xs)[i] = v;
}

// ---------------- fused per-layer kernel ----------------
__global__ __launch_bounds__(256) void k_layer(const int* __restrict__ rowstart,
                                               const int* __restrict__ deg,
                                               const float* __restrict__ dinv,
                                               const int* __restrict__ csr,
                                               const float* __restrict__ xs_in,
                                               const float* __restrict__ W,
                                               const float* __restrict__ b,
                                               const float* __restrict__ gamma,
                                               const float* __restrict__ beta,
                                               float* __restrict__ out, int n,
                                               int scale_out) {
    __shared__ float ws[DIM * DIM];
    __shared__ float xs[64 * XS_STRIDE];
    int t = threadIdx.x;
    int base = blockIdx.x * 64;

    {   // stage W
        const float4* W4 = (const float4*)W;
        float4* ws4 = (float4*)ws;
#pragma unroll
        for (int i = 0; i < 4; i++) ws4[t + 256 * i] = W4[t + 256 * i];
    }

    int wave = t >> 6;
    int lane = t & 63;

    // preload row metadata for this wave's 16 rows (broadcast later via shfl)
    int rs = 0, dg = 0;
    float dvl = 0.f;
    {
        int row = base + wave * 16 + (lane & 15);
        if (row < n) { rs = rowstart[row]; dg = deg[row]; dvl = dinv[row]; }
    }

    // ---- phase 1: aggregation into LDS tile ----
    for (int r = 0; r < 16; r++) {
        int lrow = wave * 16 + r;
        int row = base + lrow;
        float acc0 = 0.f;
        if (row < n) {
            int s0  = __shfl(rs, r, 64);
            int cnt = __shfl(dg, r, 64);
            float dv = __shfl(dvl, r, 64);
            acc0 = xs_in[(size_t)row * DIM + lane];   // self-loop (pre-scaled)
            float a1 = 0.f, a2 = 0.f, a3 = 0.f, a4 = 0.f, a5 = 0.f, a6 = 0.f, a7 = 0.f;
            int i = 0;
            for (; i + 8 <= cnt; i += 8) {
                int e0 = csr[s0 + i + 0];
                int e1 = csr[s0 + i + 1];
                int e2 = csr[s0 + i + 2];
                int e3 = csr[s0 + i + 3];
                int e4 = csr[s0 + i + 4];
                int e5 = csr[s0 + i + 5];
                int e6 = csr[s0 + i + 6];
                int e7 = csr[s0 + i + 7];
                acc0 += xs_in[(size_t)e0 * DIM + lane];
                a1   += xs_in[(size_t)e1 * DIM + lane];
                a2   += xs_in[(size_t)e2 * DIM + lane];
                a3   += xs_in[(size_t)e3 * DIM + lane];
                a4   += xs_in[(size_t)e4 * DIM + lane];
                a5   += xs_in[(size_t)e5 * DIM + lane];
                a6   += xs_in[(size_t)e6 * DIM + lane];
                a7   += xs_in[(size_t)e7 * DIM + lane];
            }
            for (; i < cnt; i++) a1 += xs_in[(size_t)csr[s0 + i] * DIM + lane];
            acc0 = ((acc0 + a1) + (a2 + a3) + ((a4 + a5) + (a6 + a7))) * dv;
        }
        xs[lrow * XS_STRIDE + lane] = acc0;
    }
    __syncthreads();

    // ---- phase 2: register-tile GEMM + epilogue ----
    int rgrp = lane >> 4;
    int c4 = lane & 15;
    int row0 = wave * 16 + rgrp * 4;

    float4 acc[4];
#pragma unroll
    for (int j = 0; j < 4; j++) acc[j] = make_float4(0.f, 0.f, 0.f, 0.f);

    for (int kc = 0; kc < 16; kc++) {
        float4 w0 = *(const float4*)(ws + (4 * kc + 0) * DIM + c4 * 4);
        float4 w1 = *(const float4*)(ws + (4 * kc + 1) * DIM + c4 * 4);
        float4 w2 = *(const float4*)(ws + (4 * kc + 2) * DIM + c4 * 4);
        float4 w3 = *(const float4*)(ws + (4 * kc + 3) * DIM + c4 * 4);
#pragma unroll
        for (int j = 0; j < 4; j++) {
            float4 xv = *(const float4*)(xs + (row0 + j) * XS_STRIDE + kc * 4);
            acc[j].x = fmaf(xv.x, w0.x, acc[j].x);
            acc[j].y = fmaf(xv.x, w0.y, acc[j].y);
            acc[j].z = fmaf(xv.x, w0.z, acc[j].z);
            acc[j].w = fmaf(xv.x, w0.w, acc[j].w);
            acc[j].x = fmaf(xv.y, w1.x, acc[j].x);
            acc[j].y = fmaf(xv.y, w1.y, acc[j].y);
            acc[j].z = fmaf(xv.y, w1.z, acc[j].z);
            acc[j].w = fmaf(xv.y, w1.w, acc[j].w);
            acc[j].x = fmaf(xv.z, w2.x, acc[j].x);
            acc[j].y = fmaf(xv.z, w2.y, acc[j].y);
            acc[j].z = fmaf(xv.z, w2.z, acc[j].z);
            acc[j].w = fmaf(xv.z, w2.w, acc[j].w);
            acc[j].x = fmaf(xv.w, w3.x, acc[j].x);
            acc[j].y = fmaf(xv.w, w3.y, acc[j].y);
            acc[j].z = fmaf(xv.w, w3.z, acc[j].z);
            acc[j].w = fmaf(xv.w, w3.w, acc[j].w);
        }
    }

    float4 b4  = *(const float4*)(b + c4 * 4);
    float4 g4  = *(const float4*)(gamma + c4 * 4);
    float4 be4 = *(const float4*)(beta + c4 * 4);
#pragma unroll
    for (int j = 0; j < 4; j++) {
        int grow = base + row0 + j;
        if (grow >= n) continue;
        float4 v = make_float4(acc[j].x + b4.x, acc[j].y + b4.y,
                               acc[j].z + b4.z, acc[j].w + b4.w);
        float s = v.x + v.y + v.z + v.w;
        s += __shfl_xor(s, 1, 64);
        s += __shfl_xor(s, 2, 64);
        s += __shfl_xor(s, 4, 64);
        s += __shfl_xor(s, 8, 64);
        float mu = s * (1.0f / 64.0f);
        float4 d = make_float4(v.x - mu, v.y - mu, v.z - mu, v.w - mu);
        float q = d.x * d.x + d.y * d.y + d.z * d.z + d.w * d.w;
        q += __shfl_xor(q, 1, 64);
        q += __shfl_xor(q, 2, 64);
        q += __shfl_xor(q, 4, 64);
        q += __shfl_xor(q, 8, 64);
        float rstd = rsqrtf(q * (1.0f / 64.0f) + LN_EPS);
        float4 y = make_float4(fmaxf(fmaf(d.x * rstd, g4.x, be4.x), 0.f),
                               fmaxf(fmaf(d.y * rstd, g4.y, be4.y), 0.f),
                               fmaxf(fmaf(d.z * rstd, g4.z, be4.z), 0.f),
                               fmaxf(fmaf(d.w * rstd, g4.w, be4.w), 0.f));
        if (scale_out) {
            float dr = dinv[grow];
            y.x *= dr; y.y *= dr; y.z *= dr; y.w *= dr;
        }
        *(float4*)(out + (size_t)grow * DIM + c4 * 4) = y;
    }
}

// ---------------- launch ----------------

extern "C" void kernel_launch(void* const* d_in, const int* in_sizes, int n_in,
                              void* d_out, int out_size, void* d_ws, size_t ws_size,
                              hipStream_t stream) {
    const float* x      = (const float*)d_in[0];
    const int*   ei     = (const int*)  d_in[1];
    const float* Ws     = (const float*)d_in[2];
    const float* bs     = (const float*)d_in[3];
    const float* gammas = (const float*)d_in[4];
    const float* betas  = (const float*)d_in[5];
    float* out = (float*)d_out;

    int n = in_sizes[0] / DIM;
    int E = in_sizes[1] / 2;
    int n_layers = in_sizes[2] / (DIM * DIM);
    int nb = (n + 63) / 64;    // buckets == k_layer tiles

    const int* srcp = ei;
    const int* dstp = ei + E;

    // ws: bcnt[nb+1] | bfill[nb+1] | bstart[nb+1] | deg[n] | rowstart[n] | dinv[n]
    //     | ebuf[E] | csr[E] | xsA[n*64]
    int* bcnt     = (int*)d_ws;
    int* bfill    = bcnt + (nb + 1);
    int* bstart   = bfill + (nb + 1);
    int* deg      = bstart + (nb + 1);
    int* rowstart = deg + n;
    float* dinv   = (float*)(rowstart + n);
    int* ebuf     = (int*)(dinv + n);
    int* csr      = ebuf + E;
    float* xsA    = (float*)(csr + E);

    int nb_ea = (E + EPB - 1) / EPB;

    k_zero2 <<<(nb + 1 + 255) / 256, 256, 0, stream>>>(bcnt, bfill, nb + 1);
    k_countb<<<nb_ea, 256, 0, stream>>>(dstp, bcnt, E, nb);
    k_scanb <<<1, 256, 0, stream>>>(bcnt, bstart, nb);
    k_binA  <<<nb_ea, 256, 0, stream>>>(srcp, dstp, bstart, bfill, ebuf, E, nb);
    k_binB  <<<nb, 256, 0, stream>>>(bstart, ebuf, deg, rowstart, dinv, csr, n);

    // ping-pong so layer (n_layers-1) lands in d_out
    float* buf0 = ((n_layers & 1) == 0) ? out : xsA;
    k_prescale<<<(n * 16 + 255) / 256, 256, 0, stream>>>(x, dinv, buf0, n * 16);

    float* cur = buf0;
    for (int i = 0; i < n_layers; i++) {
        float* dst = (cur == xsA) ? out : xsA;
        if (i == n_layers - 1) dst = out;
        int scale = (i == n_layers - 1) ? 0 : 1;
        k_layer<<<nb, 256, 0, stream>>>(rowstart, deg, dinv, csr, cur,
                                        Ws + (size_t)i * DIM * DIM,
                                        bs + (size_t)i * DIM,
                                        gammas + (size_t)i * DIM,
                                        betas + (size_t)i * DIM,
                                        dst, n, scale);
        cur = dst;
    }
}